// Round 3
// baseline (227.285 us; speedup 1.0000x reference)
//
#include <hip/hip_runtime.h>
#include <cstdint>
#include <cstddef>

typedef __bf16 bf16_t;
typedef bf16_t bf16x8 __attribute__((ext_vector_type(8)));
typedef float f32x4 __attribute__((ext_vector_type(4)));
typedef unsigned short u16x8 __attribute__((ext_vector_type(8)));
typedef unsigned short u16x4 __attribute__((ext_vector_type(4)));

#define SEQ 4096
#define BATCH 8
#define NTOK 32768      // BATCH*SEQ
#define NQKV 1536
#define DMODEL 512
#define NBH 64          // BATCH*HEADS
#define NCHUNK 8

__device__ __forceinline__ unsigned short f2b(float f) {
    union { float f; unsigned u; } c; c.f = f;
    unsigned u = c.u;
    u += 0x7fffu + ((u >> 16) & 1u);   // round-to-nearest-even
    return (unsigned short)(u >> 16);
}
__device__ __forceinline__ float b2f(unsigned short h) {
    union { unsigned u; float f; } c; c.u = ((unsigned)h) << 16;
    return c.f;
}
__device__ __forceinline__ float feat(float v) {   // elu(v)+1
    return v > 0.f ? v + 1.f : __expf(v);
}

// async global->LDS, 16B per lane; LDS dest is wave-uniform base + lane*16
__device__ __forceinline__ void gload16(const unsigned short* g, unsigned short* lds_base) {
    __builtin_amdgcn_global_load_lds((const __attribute__((address_space(1))) unsigned int*)g,
                                     (__attribute__((address_space(3))) unsigned int*)lds_base,
                                     16, 0, 0);
}

// ---------------- prep: fp32 -> bf16 for x and both weights ----------------
__global__ __launch_bounds__(256) void prep_kernel(const float* __restrict__ x,
                                                   const float* __restrict__ wqkv,
                                                   const float* __restrict__ wout,
                                                   unsigned short* __restrict__ xB,
                                                   unsigned short* __restrict__ wqkvB,
                                                   unsigned short* __restrict__ woutB) {
    const int stride = gridDim.x * 256;
    const int t0 = blockIdx.x * 256 + threadIdx.x;
    for (int j = t0; j < NTOK * DMODEL / 4; j += stride) {
        f32x4 v = ((const f32x4*)x)[j];
        u16x4 o = { f2b(v[0]), f2b(v[1]), f2b(v[2]), f2b(v[3]) };
        ((u16x4*)xB)[j] = o;
    }
    for (int j = t0; j < NQKV * DMODEL / 4; j += stride) {
        f32x4 v = ((const f32x4*)wqkv)[j];
        u16x4 o = { f2b(v[0]), f2b(v[1]), f2b(v[2]), f2b(v[3]) };
        ((u16x4*)wqkvB)[j] = o;
    }
    for (int j = t0; j < DMODEL * DMODEL / 4; j += stride) {
        f32x4 v = ((const f32x4*)wout)[j];
        u16x4 o = { f2b(v[0]), f2b(v[1]), f2b(v[2]), f2b(v[3]) };
        ((u16x4*)woutB)[j] = o;
    }
}

// ---------------- MFMA GEMM: C = A @ B^T, A bf16 [M][K], B bf16 [N][K] ----------------
// m97 structure + T3-minimum 2-phase pipeline: 128x128 tile, BK=64, double-buffered LDS,
// global_load_lds w=16, T2 XOR-swizzle, T1 XCD swizzle. One barrier per K-step.
// MODE 0: epilogue feature-map on q/k ranges, store bf16 qkvF [M][1536]
// MODE 1: epilogue + bias, store fp32 out [M][512]
template <int MODE>
__global__ __launch_bounds__(256) void gemm_kernel(const unsigned short* __restrict__ A,
                                                   const unsigned short* __restrict__ B,
                                                   void* __restrict__ Cp,
                                                   const float* __restrict__ bias,
                                                   int M, int N, int K, int nColBlocks) {
    __shared__ unsigned short As_[2][128 * 64];
    __shared__ unsigned short Bs_[2][128 * 64];
    const int tid = threadIdx.x;
    // bijective XCD swizzle (grid divisible by 8): each XCD gets a contiguous tile range
    const int nwg = gridDim.x;
    int bid = blockIdx.x;
    if ((nwg & 7) == 0) bid = (bid & 7) * (nwg >> 3) + (bid >> 3);
    const int brow = bid / nColBlocks, bcol = bid % nColBlocks;
    const int rowBase = brow * 128, colBase = bcol * 128;
    const int lane = tid & 63, wv = tid >> 6;
    const int wm = wv >> 1, wn = wv & 1;
    const int lr = lane & 15, lk = lane >> 4;

    // staging coords: each wave stages 8 contiguous rows per issue (1024B linear LDS)
    const int srow = (wv << 3) + (lane >> 3);   // + i*32
    const int sslot = lane & 7;
    // fragment read swizzle
    const int xorv = (lr & 7) << 4;

    f32x4 acc[4][4] = {};

    const unsigned short* Arow = A + (size_t)rowBase * K;
    const unsigned short* Brow = B + (size_t)colBase * K;

    auto stage = [&](int buf, int kt) {
        #pragma unroll
        for (int i = 0; i < 4; ++i) {
            int row = i * 32 + srow;
            int scol = ((sslot ^ (row & 7)) << 3) + kt;
            gload16(Arow + (size_t)row * K + scol, &As_[buf][(i * 32 + (wv << 3)) * 64]);
        }
        #pragma unroll
        for (int i = 0; i < 4; ++i) {
            int row = i * 32 + srow;
            int scol = ((sslot ^ (row & 7)) << 3) + kt;
            gload16(Brow + (size_t)row * K + scol, &Bs_[buf][(i * 32 + (wv << 3)) * 64]);
        }
    };
    auto compute = [&](int buf) {
        #pragma unroll
        for (int kk = 0; kk < 2; ++kk) {
            bf16x8 af[4], bfr[4];
            #pragma unroll
            for (int mi = 0; mi < 4; ++mi) {
                int row = wm * 64 + mi * 16 + lr;
                af[mi] = *(const bf16x8*)((const char*)&As_[buf][0] + row * 128 + ((kk * 64 + lk * 16) ^ xorv));
            }
            #pragma unroll
            for (int ni = 0; ni < 4; ++ni) {
                int row = wn * 64 + ni * 16 + lr;
                bfr[ni] = *(const bf16x8*)((const char*)&Bs_[buf][0] + row * 128 + ((kk * 64 + lk * 16) ^ xorv));
            }
            #pragma unroll
            for (int mi = 0; mi < 4; ++mi)
                #pragma unroll
                for (int ni = 0; ni < 4; ++ni)
                    acc[mi][ni] = __builtin_amdgcn_mfma_f32_16x16x32_bf16(af[mi], bfr[ni], acc[mi][ni], 0, 0, 0);
        }
    };

    // T3-minimum 2-phase: issue STAGE(next) before compute(cur); one barrier per K-step.
    stage(0, 0);
    __syncthreads();                 // drains tile-0 loads (vmcnt(0) at barrier)
    int cur = 0;
    for (int kt = 64; kt < K; kt += 64) {
        stage(cur ^ 1, kt);          // next-tile loads fly during compute(cur)
        compute(cur);
        __syncthreads();             // drain + protect buffer reuse
        cur ^= 1;
    }
    compute(cur);

    // ---- epilogue: C/D layout col=lane&15, row=(lane>>4)*4+reg ----
    #pragma unroll
    for (int mi = 0; mi < 4; ++mi) {
        #pragma unroll
        for (int r = 0; r < 4; ++r) {
            int grow = rowBase + wm * 64 + mi * 16 + lk * 4 + r;
            #pragma unroll
            for (int ni = 0; ni < 4; ++ni) {
                int gcol = colBase + wn * 64 + ni * 16 + lr;
                float val = acc[mi][ni][r];
                if (MODE == 0) {
                    float f;
                    if (gcol < 512) f = feat(val * 0.125f);        // q: elu(q*scale)+1
                    else if (gcol < 1024) f = feat(val);           // k: elu(k)+1
                    else f = val;                                  // v raw
                    ((unsigned short*)Cp)[(size_t)grow * NQKV + gcol] = f2b(f);
                } else {
                    ((float*)Cp)[(size_t)grow * DMODEL + gcol] = val + bias[gcol];
                }
            }
        }
    }
}

// ---------------- context partials: ctxP[chunk][bh][d][e], kcP[chunk][bh][d] ----------------
__global__ __launch_bounds__(256) void ctx_kernel(const unsigned short* __restrict__ qkvF,
                                                  float* __restrict__ ctxP,
                                                  float* __restrict__ kcP) {
    const int bh = blockIdx.x >> 3;
    const int chunk = blockIdx.x & 7;
    const int b = bh >> 3, h = bh & 7;
    const size_t rowBase = (size_t)b * SEQ + (size_t)chunk * (SEQ / NCHUNK);
    const unsigned short* kb = qkvF + rowBase * NQKV + 512 + h * 64;
    const unsigned short* vb = qkvF + rowBase * NQKV + 1024 + h * 64;
    __shared__ unsigned short kt_[32][64];
    __shared__ unsigned short vt_[32][64];
    const int t = threadIdx.x;
    const int lr = t >> 3, lc8 = (t & 7) * 8;
    const int d0 = (t >> 4) * 4, e0 = (t & 15) * 4;
    float acc[4][4] = {};
    float kacc[4] = {};
    for (int n0 = 0; n0 < SEQ / NCHUNK; n0 += 32) {
        __syncthreads();
        *(u16x8*)&kt_[lr][lc8] = *(const u16x8*)&kb[(size_t)(n0 + lr) * NQKV + lc8];
        *(u16x8*)&vt_[lr][lc8] = *(const u16x8*)&vb[(size_t)(n0 + lr) * NQKV + lc8];
        __syncthreads();
        #pragma unroll 4
        for (int nn = 0; nn < 32; ++nn) {
            u16x4 k4 = *(const u16x4*)&kt_[nn][d0];
            u16x4 v4 = *(const u16x4*)&vt_[nn][e0];
            float kv[4], vv[4];
            #pragma unroll
            for (int i = 0; i < 4; ++i) { kv[i] = b2f(k4[i]); vv[i] = b2f(v4[i]); }
            #pragma unroll
            for (int i = 0; i < 4; ++i)
                #pragma unroll
                for (int j = 0; j < 4; ++j)
                    acc[i][j] += kv[i] * vv[j];
            if (e0 == 0) {
                #pragma unroll
                for (int i = 0; i < 4; ++i) kacc[i] += kv[i];
            }
        }
    }
    float* cp = ctxP + ((size_t)chunk * NBH + bh) * 4096;
    #pragma unroll
    for (int i = 0; i < 4; ++i)
        #pragma unroll
        for (int j = 0; j < 4; ++j)
            cp[(d0 + i) * 64 + e0 + j] = acc[i][j];
    if (e0 == 0) {
        float* kp = kcP + ((size_t)chunk * NBH + bh) * 64;
        #pragma unroll
        for (int i = 0; i < 4; ++i) kp[d0 + i] = kacc[i];
    }
}

// ---------------- reduce partials in place into chunk-0 slots ----------------
// Each block owns one bh; reads its 8 chunk slices, writes reduced result into
// chunk-0 slice. Race-free: reads complete (in registers) before the store.
__global__ __launch_bounds__(256) void reduce_kernel(float* __restrict__ ctxP,
                                                     float* __restrict__ kcP) {
    const int bh = blockIdx.x;
    const int t = threadIdx.x;
    #pragma unroll
    for (int p = 0; p < 4; ++p) {
        int idx = p * 256 + t;
        f32x4 s = {0.f, 0.f, 0.f, 0.f};
        for (int c = 0; c < NCHUNK; ++c)
            s += ((const f32x4*)(ctxP + ((size_t)c * NBH + bh) * 4096))[idx];
        ((f32x4*)(ctxP + (size_t)bh * 4096))[idx] = s;
    }
    if (t < 64) {
        float s = 0.f;
        for (int c = 0; c < NCHUNK; ++c) s += kcP[((size_t)c * NBH + bh) * 64 + t];
        kcP[(size_t)bh * 64 + t] = s;
    }
}

// ---------------- attention out: inner = (q @ ctx) / (q . kc), bf16 [M][512] ----------------
__global__ __launch_bounds__(256) void attn_kernel(const unsigned short* __restrict__ qkvF,
                                                   const float* __restrict__ ctxR,
                                                   const float* __restrict__ kcR,
                                                   unsigned short* __restrict__ inner) {
    const int bh = blockIdx.x >> 6;
    const int rt = blockIdx.x & 63;
    const int b = bh >> 3, h = bh & 7;
    const size_t rowBase = (size_t)b * SEQ + (size_t)rt * 64;
    __shared__ float ctxs[64][64];
    __shared__ float kcs[64];
    __shared__ float dens[64];
    __shared__ unsigned short qt[64][64];
    const int t = threadIdx.x;
    #pragma unroll
    for (int p = 0; p < 4; ++p)
        ((f32x4*)&ctxs[0][0])[p * 256 + t] = ((const f32x4*)(ctxR + (size_t)bh * 4096))[p * 256 + t];
    if (t < 64) kcs[t] = kcR[(size_t)bh * 64 + t];
    const unsigned short* qg = qkvF + rowBase * NQKV + h * 64;
    #pragma unroll
    for (int p = 0; p < 2; ++p) {
        int idx = p * 256 + t;
        int r = idx >> 3, c8 = (idx & 7) * 8;
        *(u16x8*)&qt[r][c8] = *(const u16x8*)&qg[(size_t)r * NQKV + c8];
    }
    __syncthreads();
    if (t < 64) {
        float s = 1e-8f;
        for (int d = 0; d < 64; ++d) s += b2f(qt[t][d]) * kcs[d];
        dens[t] = s;
    }
    __syncthreads();
    const int r0 = (t >> 4) * 4, e0 = (t & 15) * 4;
    float acc[4][4] = {};
    for (int d = 0; d < 64; ++d) {
        f32x4 c4 = *(const f32x4*)&ctxs[d][e0];
        #pragma unroll
        for (int ri = 0; ri < 4; ++ri) {
            float qv = b2f(qt[r0 + ri][d]);
            #pragma unroll
            for (int ei = 0; ei < 4; ++ei) acc[ri][ei] += qv * c4[ei];
        }
    }
    #pragma unroll
    for (int ri = 0; ri < 4; ++ri) {
        float inv = 1.f / dens[r0 + ri];
        u16x4 o = { f2b(acc[ri][0] * inv), f2b(acc[ri][1] * inv),
                    f2b(acc[ri][2] * inv), f2b(acc[ri][3] * inv) };
        *(u16x4*)&inner[(rowBase + r0 + ri) * DMODEL + h * 64 + e0] = o;
    }
}

extern "C" void kernel_launch(void* const* d_in, const int* in_sizes, int n_in,
                              void* d_out, int out_size, void* d_ws, size_t ws_size,
                              hipStream_t stream) {
    (void)in_sizes; (void)n_in; (void)out_size; (void)ws_size;
    const float* x    = (const float*)d_in[0];
    const float* wqkv = (const float*)d_in[1];
    const float* wout = (const float*)d_in[2];
    const float* bout = (const float*)d_in[3];

    char* w = (char*)d_ws;
    // xB aliases inner: xB dead after gemm<0>; inner written by attn_kernel later.
    unsigned short* xB    = (unsigned short*)(w);                 // 32768*512*2  = 33554432
    unsigned short* inner = (unsigned short*)(w);                 // alias
    unsigned short* qkvF  = (unsigned short*)(w + 33554432);      // 32768*1536*2 = 100663296
    unsigned short* wqkvB = (unsigned short*)(w + 134217728);     // 1536*512*2   = 1572864
    unsigned short* woutB = (unsigned short*)(w + 135790592);     // 512*512*2    = 524288
    float*          ctxP  = (float*)(w + 136314880);              // 8*64*4096*4  = 8388608
    float*          kcP   = (float*)(w + 144703488);              // 8*64*64*4    = 131072
    // total ws usage: 144834560 bytes

    hipLaunchKernelGGL(prep_kernel, dim3(2048), dim3(256), 0, stream,
                       x, wqkv, wout, xB, wqkvB, woutB);
    hipLaunchKernelGGL((gemm_kernel<0>), dim3(256 * 12), dim3(256), 0, stream,
                       xB, wqkvB, (void*)qkvF, (const float*)nullptr,
                       NTOK, NQKV, DMODEL, 12);
    hipLaunchKernelGGL(ctx_kernel, dim3(NBH * NCHUNK), dim3(256), 0, stream, qkvF, ctxP, kcP);
    hipLaunchKernelGGL(reduce_kernel, dim3(NBH), dim3(256), 0, stream, ctxP, kcP);
    hipLaunchKernelGGL(attn_kernel, dim3(NBH * 64), dim3(256), 0, stream, qkvF, ctxP, kcP, inner);
    hipLaunchKernelGGL((gemm_kernel<1>), dim3(256 * 4), dim3(256), 0, stream,
                       inner, woutB, (void*)d_out, bout,
                       NTOK, DMODEL, DMODEL, 4);
}

// Round 4
// 212.796 us; speedup vs baseline: 1.0681x; 1.0681x over previous
//
#include <hip/hip_runtime.h>
#include <cstdint>
#include <cstddef>

typedef __bf16 bf16_t;
typedef bf16_t bf16x8 __attribute__((ext_vector_type(8)));
typedef float f32x4 __attribute__((ext_vector_type(4)));
typedef unsigned short u16x8 __attribute__((ext_vector_type(8)));
typedef unsigned short u16x4 __attribute__((ext_vector_type(4)));

#define SEQ 4096
#define BATCH 8
#define NTOK 32768      // BATCH*SEQ
#define NQKV 1536
#define DMODEL 512
#define NBH 64          // BATCH*HEADS
#define NCHUNK 8

__device__ __forceinline__ unsigned short f2b(float f) {
    union { float f; unsigned u; } c; c.f = f;
    unsigned u = c.u;
    u += 0x7fffu + ((u >> 16) & 1u);   // round-to-nearest-even
    return (unsigned short)(u >> 16);
}
__device__ __forceinline__ float b2f(unsigned short h) {
    union { unsigned u; float f; } c; c.u = ((unsigned)h) << 16;
    return c.f;
}
__device__ __forceinline__ float feat(float v) {   // elu(v)+1
    return v > 0.f ? v + 1.f : __expf(v);
}

// async global->LDS, 16B per lane; LDS dest is wave-uniform base + lane*16
__device__ __forceinline__ void gload16(const unsigned short* g, unsigned short* lds_base) {
    __builtin_amdgcn_global_load_lds((const __attribute__((address_space(1))) unsigned int*)g,
                                     (__attribute__((address_space(3))) unsigned int*)lds_base,
                                     16, 0, 0);
}

// ---------------- prep: fp32 -> bf16 for x and both weights ----------------
__global__ __launch_bounds__(256) void prep_kernel(const float* __restrict__ x,
                                                   const float* __restrict__ wqkv,
                                                   const float* __restrict__ wout,
                                                   unsigned short* __restrict__ xB,
                                                   unsigned short* __restrict__ wqkvB,
                                                   unsigned short* __restrict__ woutB) {
    const int stride = gridDim.x * 256;
    const int t0 = blockIdx.x * 256 + threadIdx.x;
    for (int j = t0; j < NTOK * DMODEL / 4; j += stride) {
        f32x4 v = ((const f32x4*)x)[j];
        u16x4 o = { f2b(v[0]), f2b(v[1]), f2b(v[2]), f2b(v[3]) };
        ((u16x4*)xB)[j] = o;
    }
    for (int j = t0; j < NQKV * DMODEL / 4; j += stride) {
        f32x4 v = ((const f32x4*)wqkv)[j];
        u16x4 o = { f2b(v[0]), f2b(v[1]), f2b(v[2]), f2b(v[3]) };
        ((u16x4*)wqkvB)[j] = o;
    }
    for (int j = t0; j < DMODEL * DMODEL / 4; j += stride) {
        f32x4 v = ((const f32x4*)wout)[j];
        u16x4 o = { f2b(v[0]), f2b(v[1]), f2b(v[2]), f2b(v[3]) };
        ((u16x4*)woutB)[j] = o;
    }
}

// one 16x16x32 quadrant cluster: compile-time MH/NH so acc indexing stays static (rule #20)
template <int MH, int NH>
__device__ __forceinline__ void quad(const bf16x8 (&af)[4][2], const bf16x8 (&bf)[2][2],
                                     f32x4 (&acc)[8][4]) {
    #pragma unroll
    for (int mi = 0; mi < 4; ++mi)
        #pragma unroll
        for (int ni = 0; ni < 2; ++ni)
            #pragma unroll
            for (int kk = 0; kk < 2; ++kk)
                acc[MH * 4 + mi][NH * 2 + ni] =
                    __builtin_amdgcn_mfma_f32_16x16x32_bf16(af[mi][kk], bf[ni][kk],
                                                            acc[MH * 4 + mi][NH * 2 + ni], 0, 0, 0);
}

// ---------------- MFMA GEMM: C = A @ B^T, A bf16 [M][K], B bf16 [N][K] ----------------
// 256x256 8-phase template (T3+T4+T5): BK=64, 8 waves (2Mx4N), 128KiB LDS dbuf,
// raw s_barrier + counted vmcnt(2) once per K-tile (never 0 in loop), setprio
// around each 16-MFMA quadrant, T2 XOR-swizzle, T1 XCD swizzle.
// MODE 0: epilogue feature-map on q/k ranges, store bf16 qkvF [M][1536]
// MODE 1: epilogue + bias, store fp32 out [M][512]
template <int MODE>
__global__ __launch_bounds__(512) void gemm_kernel(const unsigned short* __restrict__ A,
                                                   const unsigned short* __restrict__ B,
                                                   void* __restrict__ Cp,
                                                   const float* __restrict__ bias,
                                                   int M, int N, int K, int nColBlocks) {
    __shared__ __align__(16) unsigned short As_[2][16384];   // 2 x 256 x 64
    __shared__ __align__(16) unsigned short Bs_[2][16384];
    const int tid = threadIdx.x;
    const int nwg = gridDim.x;
    int bid = blockIdx.x;
    if ((nwg & 7) == 0) bid = (bid & 7) * (nwg >> 3) + (bid >> 3);
    const int brow = bid / nColBlocks, bcol = bid % nColBlocks;
    const int rowBase = brow * 256, colBase = bcol * 256;
    const int lane = tid & 63, wv = tid >> 6;          // 8 waves
    const int wm = wv >> 2, wn = wv & 3;               // 2M x 4N
    const int lr = lane & 15, lk = lane >> 4;
    const int xorv = (lr & 7) << 4;                    // T2 read-side swizzle

    const unsigned short* Arow = A + (size_t)rowBase * K;
    const unsigned short* Brow = B + (size_t)colBase * K;

    // stage one 128x64 half-tile (16KB): 2 gload16/thread, linear LDS dest,
    // pre-swizzled global source (involution matches read-side XOR).
    auto stageHalf = [&](int buf, int kt, int mat, int h) {
        const unsigned short* src = mat ? Brow : Arow;
        unsigned short* dst = mat ? &Bs_[buf][0] : &As_[buf][0];
        #pragma unroll
        for (int j = 0; j < 2; ++j) {
            int L = j * 512 + tid;
            int r = L >> 3, s = L & 7;
            int scol = ((s ^ (r & 7)) << 3) + kt;
            gload16(src + (size_t)(h * 128 + r) * K + scol,
                    dst + h * 8192 + (j * 512 + (wv << 6)) * 8);
        }
    };
    auto readA = [&](int buf, int row, int kk) -> bf16x8 {
        return *(const bf16x8*)((const char*)&As_[buf][0] + row * 128 + ((kk * 64 + lk * 16) ^ xorv));
    };
    auto readB = [&](int buf, int row, int kk) -> bf16x8 {
        return *(const bf16x8*)((const char*)&Bs_[buf][0] + row * 128 + ((kk * 64 + lk * 16) ^ xorv));
    };

    f32x4 acc[8][4] = {};
    bf16x8 af[4][2], bfA[2][2], bfB[2][2];

    const int NT = K >> 6;
    // prologue: stage tile 0 fully (A halves first: HBM latency; B halves: L2)
    stageHalf(0, 0, 0, 0); stageHalf(0, 0, 0, 1);
    stageHalf(0, 0, 1, 0); stageHalf(0, 0, 1, 1);

    for (int t = 0; t < NT; ++t) {
        const int buf = t & 1;
        const int obuf = buf ^ 1;
        const int ktn = (t + 1) << 6;
        const bool pre = (t + 1 < NT);

        // ---- group start: issue next tile's first half, counted wait for tile t ----
        if (pre) {
            stageHalf(obuf, ktn, 0, 0);                       // A-half0 of t+1
            asm volatile("s_waitcnt vmcnt(2)" ::: "memory");  // tile-t halves landed; 2 fly
        } else {
            asm volatile("s_waitcnt vmcnt(0)" ::: "memory");
        }
        __builtin_amdgcn_s_barrier();
        __builtin_amdgcn_sched_barrier(0);

        // ---- phase 0: quadrant (0,0) ----
        #pragma unroll
        for (int mi = 0; mi < 4; ++mi)
            #pragma unroll
            for (int kk = 0; kk < 2; ++kk)
                af[mi][kk] = readA(buf, wm * 128 + mi * 16 + lr, kk);
        #pragma unroll
        for (int ni = 0; ni < 2; ++ni)
            #pragma unroll
            for (int kk = 0; kk < 2; ++kk)
                bfA[ni][kk] = readB(buf, wn * 64 + ni * 16 + lr, kk);
        asm volatile("s_waitcnt lgkmcnt(0)" ::: "memory");
        __builtin_amdgcn_sched_barrier(0);
        __builtin_amdgcn_s_setprio(1);
        quad<0, 0>(af, bfA, acc);
        __builtin_amdgcn_s_setprio(0);
        __builtin_amdgcn_s_barrier();
        __builtin_amdgcn_sched_barrier(0);

        // ---- phase 1: quadrant (0,1) ----
        #pragma unroll
        for (int ni = 0; ni < 2; ++ni)
            #pragma unroll
            for (int kk = 0; kk < 2; ++kk)
                bfB[ni][kk] = readB(buf, wn * 64 + 32 + ni * 16 + lr, kk);
        if (pre) stageHalf(obuf, ktn, 0, 1);                  // A-half1 of t+1
        asm volatile("s_waitcnt lgkmcnt(0)" ::: "memory");
        __builtin_amdgcn_sched_barrier(0);
        __builtin_amdgcn_s_setprio(1);
        quad<0, 1>(af, bfB, acc);
        __builtin_amdgcn_s_setprio(0);
        __builtin_amdgcn_s_barrier();
        __builtin_amdgcn_sched_barrier(0);

        // ---- phase 2: quadrant (1,0) ----
        #pragma unroll
        for (int mi = 0; mi < 4; ++mi)
            #pragma unroll
            for (int kk = 0; kk < 2; ++kk)
                af[mi][kk] = readA(buf, wm * 128 + 64 + mi * 16 + lr, kk);
        if (pre) stageHalf(obuf, ktn, 1, 0);                  // B-half0 of t+1
        asm volatile("s_waitcnt lgkmcnt(0)" ::: "memory");
        __builtin_amdgcn_sched_barrier(0);
        __builtin_amdgcn_s_setprio(1);
        quad<1, 0>(af, bfA, acc);
        __builtin_amdgcn_s_setprio(0);
        __builtin_amdgcn_s_barrier();
        __builtin_amdgcn_sched_barrier(0);

        // ---- phase 3: quadrant (1,1), no new LDS reads ----
        if (pre) stageHalf(obuf, ktn, 1, 1);                  // B-half1 of t+1
        __builtin_amdgcn_s_setprio(1);
        quad<1, 1>(af, bfB, acc);
        __builtin_amdgcn_s_setprio(0);
        __builtin_amdgcn_s_barrier();                          // frees buf for t+2 staging
        __builtin_amdgcn_sched_barrier(0);
    }

    // ---- epilogue: C/D layout col=lane&15, row=(lane>>4)*4+reg ----
    #pragma unroll
    for (int MI = 0; MI < 8; ++MI) {
        #pragma unroll
        for (int r = 0; r < 4; ++r) {
            int grow = rowBase + wm * 128 + MI * 16 + lk * 4 + r;
            #pragma unroll
            for (int NI = 0; NI < 4; ++NI) {
                int gcol = colBase + wn * 64 + NI * 16 + lr;
                float val = acc[MI][NI][r];
                if (MODE == 0) {
                    float f;
                    if (gcol < 512) f = feat(val * 0.125f);        // q: elu(q*scale)+1
                    else if (gcol < 1024) f = feat(val);           // k: elu(k)+1
                    else f = val;                                  // v raw
                    ((unsigned short*)Cp)[(size_t)grow * NQKV + gcol] = f2b(f);
                } else {
                    ((float*)Cp)[(size_t)grow * DMODEL + gcol] = val + bias[gcol];
                }
            }
        }
    }
}

// ---------------- context partials: ctxP[chunk][bh][d][e], kcP[chunk][bh][d] ----------------
__global__ __launch_bounds__(256) void ctx_kernel(const unsigned short* __restrict__ qkvF,
                                                  float* __restrict__ ctxP,
                                                  float* __restrict__ kcP) {
    const int bh = blockIdx.x >> 3;
    const int chunk = blockIdx.x & 7;
    const int b = bh >> 3, h = bh & 7;
    const size_t rowBase = (size_t)b * SEQ + (size_t)chunk * (SEQ / NCHUNK);
    const unsigned short* kb = qkvF + rowBase * NQKV + 512 + h * 64;
    const unsigned short* vb = qkvF + rowBase * NQKV + 1024 + h * 64;
    __shared__ unsigned short kt_[32][64];
    __shared__ unsigned short vt_[32][64];
    const int t = threadIdx.x;
    const int lr = t >> 3, lc8 = (t & 7) * 8;
    const int d0 = (t >> 4) * 4, e0 = (t & 15) * 4;
    float acc[4][4] = {};
    float kacc[4] = {};
    for (int n0 = 0; n0 < SEQ / NCHUNK; n0 += 32) {
        __syncthreads();
        *(u16x8*)&kt_[lr][lc8] = *(const u16x8*)&kb[(size_t)(n0 + lr) * NQKV + lc8];
        *(u16x8*)&vt_[lr][lc8] = *(const u16x8*)&vb[(size_t)(n0 + lr) * NQKV + lc8];
        __syncthreads();
        #pragma unroll 4
        for (int nn = 0; nn < 32; ++nn) {
            u16x4 k4 = *(const u16x4*)&kt_[nn][d0];
            u16x4 v4 = *(const u16x4*)&vt_[nn][e0];
            float kv[4], vv[4];
            #pragma unroll
            for (int i = 0; i < 4; ++i) { kv[i] = b2f(k4[i]); vv[i] = b2f(v4[i]); }
            #pragma unroll
            for (int i = 0; i < 4; ++i)
                #pragma unroll
                for (int j = 0; j < 4; ++j)
                    acc[i][j] += kv[i] * vv[j];
            if (e0 == 0) {
                #pragma unroll
                for (int i = 0; i < 4; ++i) kacc[i] += kv[i];
            }
        }
    }
    float* cp = ctxP + ((size_t)chunk * NBH + bh) * 4096;
    #pragma unroll
    for (int i = 0; i < 4; ++i)
        #pragma unroll
        for (int j = 0; j < 4; ++j)
            cp[(d0 + i) * 64 + e0 + j] = acc[i][j];
    if (e0 == 0) {
        float* kp = kcP + ((size_t)chunk * NBH + bh) * 64;
        #pragma unroll
        for (int i = 0; i < 4; ++i) kp[d0 + i] = kacc[i];
    }
}

// ---------------- reduce partials in place into chunk-0 slots ----------------
__global__ __launch_bounds__(256) void reduce_kernel(float* __restrict__ ctxP,
                                                     float* __restrict__ kcP) {
    const int bh = blockIdx.x;
    const int t = threadIdx.x;
    #pragma unroll
    for (int p = 0; p < 4; ++p) {
        int idx = p * 256 + t;
        f32x4 s = {0.f, 0.f, 0.f, 0.f};
        for (int c = 0; c < NCHUNK; ++c)
            s += ((const f32x4*)(ctxP + ((size_t)c * NBH + bh) * 4096))[idx];
        ((f32x4*)(ctxP + (size_t)bh * 4096))[idx] = s;
    }
    if (t < 64) {
        float s = 0.f;
        for (int c = 0; c < NCHUNK; ++c) s += kcP[((size_t)c * NBH + bh) * 64 + t];
        kcP[(size_t)bh * 64 + t] = s;
    }
}

// ---------------- attention out: inner = (q @ ctx) / (q . kc), bf16 [M][512] ----------------
__global__ __launch_bounds__(256) void attn_kernel(const unsigned short* __restrict__ qkvF,
                                                   const float* __restrict__ ctxR,
                                                   const float* __restrict__ kcR,
                                                   unsigned short* __restrict__ inner) {
    const int bh = blockIdx.x >> 6;
    const int rt = blockIdx.x & 63;
    const int b = bh >> 3, h = bh & 7;
    const size_t rowBase = (size_t)b * SEQ + (size_t)rt * 64;
    __shared__ float ctxs[64][64];
    __shared__ float kcs[64];
    __shared__ float dens[64];
    __shared__ unsigned short qt[64][64];
    const int t = threadIdx.x;
    #pragma unroll
    for (int p = 0; p < 4; ++p)
        ((f32x4*)&ctxs[0][0])[p * 256 + t] = ((const f32x4*)(ctxR + (size_t)bh * 4096))[p * 256 + t];
    if (t < 64) kcs[t] = kcR[(size_t)bh * 64 + t];
    const unsigned short* qg = qkvF + rowBase * NQKV + h * 64;
    #pragma unroll
    for (int p = 0; p < 2; ++p) {
        int idx = p * 256 + t;
        int r = idx >> 3, c8 = (idx & 7) * 8;
        *(u16x8*)&qt[r][c8] = *(const u16x8*)&qg[(size_t)r * NQKV + c8];
    }
    __syncthreads();
    if (t < 64) {
        float s = 1e-8f;
        for (int d = 0; d < 64; ++d) s += b2f(qt[t][d]) * kcs[d];
        dens[t] = s;
    }
    __syncthreads();
    const int r0 = (t >> 4) * 4, e0 = (t & 15) * 4;
    float acc[4][4] = {};
    for (int d = 0; d < 64; ++d) {
        f32x4 c4 = *(const f32x4*)&ctxs[d][e0];
        #pragma unroll
        for (int ri = 0; ri < 4; ++ri) {
            float qv = b2f(qt[r0 + ri][d]);
            #pragma unroll
            for (int ei = 0; ei < 4; ++ei) acc[ri][ei] += qv * c4[ei];
        }
    }
    #pragma unroll
    for (int ri = 0; ri < 4; ++ri) {
        float inv = 1.f / dens[r0 + ri];
        u16x4 o = { f2b(acc[ri][0] * inv), f2b(acc[ri][1] * inv),
                    f2b(acc[ri][2] * inv), f2b(acc[ri][3] * inv) };
        *(u16x4*)&inner[(rowBase + r0 + ri) * DMODEL + h * 64 + e0] = o;
    }
}

extern "C" void kernel_launch(void* const* d_in, const int* in_sizes, int n_in,
                              void* d_out, int out_size, void* d_ws, size_t ws_size,
                              hipStream_t stream) {
    (void)in_sizes; (void)n_in; (void)out_size; (void)ws_size;
    const float* x    = (const float*)d_in[0];
    const float* wqkv = (const float*)d_in[1];
    const float* wout = (const float*)d_in[2];
    const float* bout = (const float*)d_in[3];

    char* w = (char*)d_ws;
    // xB aliases inner: xB dead after gemm<0>; inner written by attn_kernel later.
    unsigned short* xB    = (unsigned short*)(w);                 // 32768*512*2  = 33554432
    unsigned short* inner = (unsigned short*)(w);                 // alias
    unsigned short* qkvF  = (unsigned short*)(w + 33554432);      // 32768*1536*2 = 100663296
    unsigned short* wqkvB = (unsigned short*)(w + 134217728);     // 1536*512*2   = 1572864
    unsigned short* woutB = (unsigned short*)(w + 135790592);     // 512*512*2    = 524288
    float*          ctxP  = (float*)(w + 136314880);              // 8*64*4096*4  = 8388608
    float*          kcP   = (float*)(w + 144703488);              // 8*64*64*4    = 131072
    // total ws usage: 144834560 bytes

    hipLaunchKernelGGL(prep_kernel, dim3(2048), dim3(256), 0, stream,
                       x, wqkv, wout, xB, wqkvB, woutB);
    hipLaunchKernelGGL((gemm_kernel<0>), dim3(768), dim3(512), 0, stream,
                       xB, wqkvB, (void*)qkvF, (const float*)nullptr,
                       NTOK, NQKV, DMODEL, 6);
    hipLaunchKernelGGL(ctx_kernel, dim3(NBH * NCHUNK), dim3(256), 0, stream, qkvF, ctxP, kcP);
    hipLaunchKernelGGL(reduce_kernel, dim3(NBH), dim3(256), 0, stream, ctxP, kcP);
    hipLaunchKernelGGL(attn_kernel, dim3(NBH * 64), dim3(256), 0, stream, qkvF, ctxP, kcP, inner);
    hipLaunchKernelGGL((gemm_kernel<1>), dim3(256), dim3(512), 0, stream,
                       inner, woutB, (void*)d_out, bout,
                       NTOK, DMODEL, DMODEL, 2);
}

// Round 5
// 168.790 us; speedup vs baseline: 1.3466x; 1.2607x over previous
//
#include <hip/hip_runtime.h>
#include <cstdint>
#include <cstddef>

typedef __bf16 bf16_t;
typedef bf16_t bf16x8 __attribute__((ext_vector_type(8)));
typedef float f32x4 __attribute__((ext_vector_type(4)));
typedef unsigned short u16x8 __attribute__((ext_vector_type(8)));
typedef unsigned short u16x4 __attribute__((ext_vector_type(4)));

#define SEQ 4096
#define BATCH 8
#define NTOK 32768      // BATCH*SEQ
#define NQKV 1536
#define DMODEL 512
#define NBH 64          // BATCH*HEADS
#define NCHUNK 8

__device__ __forceinline__ unsigned short f2b(float f) {
    union { float f; unsigned u; } c; c.f = f;
    unsigned u = c.u;
    u += 0x7fffu + ((u >> 16) & 1u);   // round-to-nearest-even
    return (unsigned short)(u >> 16);
}
__device__ __forceinline__ float b2f(unsigned short h) {
    union { unsigned u; float f; } c; c.u = ((unsigned)h) << 16;
    return c.f;
}
__device__ __forceinline__ float feat(float v) {   // elu(v)+1
    return v > 0.f ? v + 1.f : __expf(v);
}

// async global->LDS, 16B per lane; LDS dest is wave-uniform base + lane*16
__device__ __forceinline__ void gload16(const unsigned short* g, unsigned short* lds_base) {
    __builtin_amdgcn_global_load_lds((const __attribute__((address_space(1))) unsigned int*)g,
                                     (__attribute__((address_space(3))) unsigned int*)lds_base,
                                     16, 0, 0);
}

// ---------------- prep: fp32 -> bf16 for x and both weights ----------------
__global__ __launch_bounds__(256) void prep_kernel(const float* __restrict__ x,
                                                   const float* __restrict__ wqkv,
                                                   const float* __restrict__ wout,
                                                   unsigned short* __restrict__ xB,
                                                   unsigned short* __restrict__ wqkvB,
                                                   unsigned short* __restrict__ woutB) {
    const int stride = gridDim.x * 256;
    const int t0 = blockIdx.x * 256 + threadIdx.x;
    for (int j = t0; j < NTOK * DMODEL / 4; j += stride) {
        f32x4 v = ((const f32x4*)x)[j];
        u16x4 o = { f2b(v[0]), f2b(v[1]), f2b(v[2]), f2b(v[3]) };
        ((u16x4*)xB)[j] = o;
    }
    for (int j = t0; j < NQKV * DMODEL / 4; j += stride) {
        f32x4 v = ((const f32x4*)wqkv)[j];
        u16x4 o = { f2b(v[0]), f2b(v[1]), f2b(v[2]), f2b(v[3]) };
        ((u16x4*)wqkvB)[j] = o;
    }
    for (int j = t0; j < DMODEL * DMODEL / 4; j += stride) {
        f32x4 v = ((const f32x4*)wout)[j];
        u16x4 o = { f2b(v[0]), f2b(v[1]), f2b(v[2]), f2b(v[3]) };
        ((u16x4*)woutB)[j] = o;
    }
}

// ---------------- MFMA GEMM: C = A @ B^T, A bf16 [M][K], B bf16 [N][K] ----------------
// R2-proven structure: 128x128 tile, BK=64, single-buffer LDS, global_load_lds w=16,
// T2 XOR-swizzle (0 conflicts), T1 XCD swizzle.
// MODE 0: feature-map epilogue -> qF [tok][512] bf16; kT/vT [bh][d][4096] bf16 (transposed)
// MODE 1: +bias epilogue -> fp32 out [tok][512]   (Ck/Cv unused)
template <int MODE>
__global__ __launch_bounds__(256) void gemm_kernel(const unsigned short* __restrict__ A,
                                                   const unsigned short* __restrict__ B,
                                                   void* __restrict__ Cq,
                                                   unsigned short* __restrict__ Ck,
                                                   unsigned short* __restrict__ Cv,
                                                   const float* __restrict__ bias,
                                                   int M, int N, int K, int nColBlocks) {
    __shared__ __align__(16) unsigned short As_[128 * 64];
    __shared__ __align__(16) unsigned short Bs_[128 * 64];
    const int tid = threadIdx.x;
    const int nwg = gridDim.x;
    int bid = blockIdx.x;
    if ((nwg & 7) == 0) bid = (bid & 7) * (nwg >> 3) + (bid >> 3);
    const int brow = bid / nColBlocks, bcol = bid % nColBlocks;
    const int rowBase = brow * 128, colBase = bcol * 128;
    const int lane = tid & 63, wv = tid >> 6;
    const int wm = wv >> 1, wn = wv & 1;
    const int lr = lane & 15, lk = lane >> 4;
    const int srow = (wv << 3) + (lane >> 3);
    const int sslot = lane & 7;
    const int xorv = (lr & 7) << 4;

    f32x4 acc[4][4] = {};
    const unsigned short* Arow = A + (size_t)rowBase * K;
    const unsigned short* Brow = B + (size_t)colBase * K;

    for (int kt = 0; kt < K; kt += 64) {
        #pragma unroll
        for (int i = 0; i < 4; ++i) {
            int row = i * 32 + srow;
            int scol = ((sslot ^ (row & 7)) << 3) + kt;
            gload16(Arow + (size_t)row * K + scol, As_ + (i * 32 + (wv << 3)) * 64);
        }
        #pragma unroll
        for (int i = 0; i < 4; ++i) {
            int row = i * 32 + srow;
            int scol = ((sslot ^ (row & 7)) << 3) + kt;
            gload16(Brow + (size_t)row * K + scol, Bs_ + (i * 32 + (wv << 3)) * 64);
        }
        __syncthreads();
        #pragma unroll
        for (int kk = 0; kk < 2; ++kk) {
            bf16x8 af[4], bfr[4];
            #pragma unroll
            for (int mi = 0; mi < 4; ++mi) {
                int row = wm * 64 + mi * 16 + lr;
                af[mi] = *(const bf16x8*)((const char*)As_ + row * 128 + ((kk * 64 + lk * 16) ^ xorv));
            }
            #pragma unroll
            for (int ni = 0; ni < 4; ++ni) {
                int row = wn * 64 + ni * 16 + lr;
                bfr[ni] = *(const bf16x8*)((const char*)Bs_ + row * 128 + ((kk * 64 + lk * 16) ^ xorv));
            }
            #pragma unroll
            for (int mi = 0; mi < 4; ++mi)
                #pragma unroll
                for (int ni = 0; ni < 4; ++ni)
                    acc[mi][ni] = __builtin_amdgcn_mfma_f32_16x16x32_bf16(af[mi], bfr[ni], acc[mi][ni], 0, 0, 0);
        }
        __syncthreads();
    }

    // ---- epilogue: C/D layout col=lane&15, row=(lane>>4)*4+reg ----
    #pragma unroll
    for (int mi = 0; mi < 4; ++mi) {
        const int grow0 = rowBase + wm * 64 + mi * 16 + lk * 4;
        #pragma unroll
        for (int ni = 0; ni < 4; ++ni) {
            const int gcol = colBase + wn * 64 + ni * 16 + lr;
            if (MODE == 0) {
                if (gcol < 512) {
                    #pragma unroll
                    for (int r = 0; r < 4; ++r)
                        ((unsigned short*)Cq)[(size_t)(grow0 + r) * DMODEL + gcol] =
                            f2b(feat(acc[mi][ni][r] * 0.125f));       // q: elu(q*scale)+1
                } else if (gcol < 1024) {
                    int hd = gcol - 512;
                    int b_ = grow0 >> 12, n0 = grow0 & 4095;
                    u16x4 o = { f2b(feat(acc[mi][ni][0])), f2b(feat(acc[mi][ni][1])),
                                f2b(feat(acc[mi][ni][2])), f2b(feat(acc[mi][ni][3])) };
                    *(u16x4*)&Ck[((size_t)(b_ * 512 + hd)) * SEQ + n0] = o;   // k: elu(k)+1, [bh*64+d][n]
                } else {
                    int hd = gcol - 1024;
                    int b_ = grow0 >> 12, n0 = grow0 & 4095;
                    u16x4 o = { f2b(acc[mi][ni][0]), f2b(acc[mi][ni][1]),
                                f2b(acc[mi][ni][2]), f2b(acc[mi][ni][3]) };
                    *(u16x4*)&Cv[((size_t)(b_ * 512 + hd)) * SEQ + n0] = o;   // v raw
                }
            } else {
                #pragma unroll
                for (int r = 0; r < 4; ++r)
                    ((float*)Cq)[(size_t)(grow0 + r) * DMODEL + gcol] = acc[mi][ni][r] + bias[gcol];
            }
        }
    }
}

// ---------------- ctx (MFMA): ctxP[chunk][bh][d][e] = sum_n k[n][d] v[n][e]; kc via ones ----
__global__ __launch_bounds__(256) void ctx_kernel(const unsigned short* __restrict__ kT,
                                                  const unsigned short* __restrict__ vT,
                                                  float* __restrict__ ctxP,
                                                  float* __restrict__ kcP) {
    const int bh = blockIdx.x >> 3;
    const int chunk = blockIdx.x & 7;
    __shared__ __align__(16) unsigned short ks[64 * 64];
    __shared__ __align__(16) unsigned short vs[64 * 64];
    const int tid = threadIdx.x;
    const int lane = tid & 63, wv = tid >> 6;
    const int lr = lane & 15, lk = lane >> 4;
    const int xorv = (lr & 7) << 4;
    const int r_s = tid >> 3, s_s = tid & 7;
    const unsigned short* kg = kT + (size_t)bh * 64 * SEQ;
    const unsigned short* vg = vT + (size_t)bh * 64 * SEQ;

    f32x4 acc[4] = {};
    f32x4 kacc[4] = {};
    union { u16x8 u; bf16x8 b; } onesc;
    onesc.u = (u16x8){0x3F80, 0x3F80, 0x3F80, 0x3F80, 0x3F80, 0x3F80, 0x3F80, 0x3F80};
    const bf16x8 ones = onesc.b;

    for (int t = 0; t < 8; ++t) {
        const int n0 = chunk * 512 + t * 64;
        __syncthreads();                                  // protect prev-tile reads
        #pragma unroll
        for (int j = 0; j < 2; ++j) {
            int r = j * 32 + r_s;                         // d-row 0..63
            int scol = ((s_s ^ (r & 7)) << 3) + n0;       // pre-swizzled source
            gload16(kg + (size_t)r * SEQ + scol, ks + (j * 256 + (wv << 6)) * 8);
            gload16(vg + (size_t)r * SEQ + scol, vs + (j * 256 + (wv << 6)) * 8);
        }
        __syncthreads();                                  // drain gload16
        #pragma unroll
        for (int kk = 0; kk < 2; ++kk) {
            bf16x8 bfr = *(const bf16x8*)((const char*)vs + (wv * 16 + lr) * 128 + ((kk * 64 + lk * 16) ^ xorv));
            #pragma unroll
            for (int mi = 0; mi < 4; ++mi) {
                bf16x8 af = *(const bf16x8*)((const char*)ks + (mi * 16 + lr) * 128 + ((kk * 64 + lk * 16) ^ xorv));
                acc[mi] = __builtin_amdgcn_mfma_f32_16x16x32_bf16(af, bfr, acc[mi], 0, 0, 0);
                if (wv == 0)
                    kacc[mi] = __builtin_amdgcn_mfma_f32_16x16x32_bf16(af, ones, kacc[mi], 0, 0, 0);
            }
        }
    }
    float* cp = ctxP + ((size_t)chunk * NBH + bh) * 4096;
    #pragma unroll
    for (int mi = 0; mi < 4; ++mi)
        #pragma unroll
        for (int r = 0; r < 4; ++r)
            cp[(mi * 16 + lk * 4 + r) * 64 + wv * 16 + lr] = acc[mi][r];
    if (wv == 0 && lr == 0) {
        float* kp = kcP + ((size_t)chunk * NBH + bh) * 64;
        #pragma unroll
        for (int mi = 0; mi < 4; ++mi)
            #pragma unroll
            for (int r = 0; r < 4; ++r)
                kp[mi * 16 + lk * 4 + r] = kacc[mi][r];
    }
}

// ---------------- reduce: sum partials; emit ctxT hi/lo bf16 [bh][e][d] + kc fp32 ----------------
__global__ __launch_bounds__(256) void reduce_kernel(const float* __restrict__ ctxP,
                                                     const float* __restrict__ kcP,
                                                     unsigned short* __restrict__ cTh,
                                                     unsigned short* __restrict__ cTl,
                                                     float* __restrict__ kcR) {
    const int bh = blockIdx.x;
    const int t = threadIdx.x;
    #pragma unroll
    for (int p = 0; p < 4; ++p) {
        int idx = p * 256 + t;                            // f32x4 index; elems [d][e0..e0+3]
        f32x4 s = {0.f, 0.f, 0.f, 0.f};
        for (int c = 0; c < NCHUNK; ++c)
            s += ((const f32x4*)(ctxP + ((size_t)c * NBH + bh) * 4096))[idx];
        int d = idx >> 4, e0 = (idx & 15) * 4;
        #pragma unroll
        for (int j = 0; j < 4; ++j) {
            unsigned short hi = f2b(s[j]);
            cTh[(size_t)bh * 4096 + (e0 + j) * 64 + d] = hi;
            cTl[(size_t)bh * 4096 + (e0 + j) * 64 + d] = f2b(s[j] - b2f(hi));
        }
    }
    if (t < 64) {
        float s = 0.f;
        for (int c = 0; c < NCHUNK; ++c) s += kcP[((size_t)c * NBH + bh) * 64 + t];
        kcR[bh * 64 + t] = s;
    }
}

// ---------------- attn (MFMA): inner[n][h*64+e] = (q @ (ctx_hi+ctx_lo)) / (q . kc) ----------------
__global__ __launch_bounds__(256) void attn_kernel(const unsigned short* __restrict__ qF,
                                                   const unsigned short* __restrict__ cTh,
                                                   const unsigned short* __restrict__ cTl,
                                                   const float* __restrict__ kcR,
                                                   unsigned short* __restrict__ inner) {
    const int bh = blockIdx.x >> 6;
    const int rt = blockIdx.x & 63;
    const int b = bh >> 3, h = bh & 7;
    const size_t rowBase = (size_t)b * SEQ + (size_t)rt * 64;
    __shared__ __align__(16) unsigned short qs[64 * 64];
    __shared__ __align__(16) unsigned short chs[64 * 64];
    __shared__ __align__(16) unsigned short cls[64 * 64];
    __shared__ float dpart[64][4];
    __shared__ float dens[64];
    __shared__ float kcs[64];
    const int tid = threadIdx.x;
    const int lane = tid & 63, wv = tid >> 6;
    const int lr = lane & 15, lk = lane >> 4;
    const int xorv = (lr & 7) << 4;
    const int r_s = tid >> 3, s_s = tid & 7;

    #pragma unroll
    for (int j = 0; j < 2; ++j) {
        int r = j * 32 + r_s;
        int sc = (s_s ^ (r & 7)) << 3;
        gload16(qF + (rowBase + r) * DMODEL + h * 64 + sc, qs + (j * 256 + (wv << 6)) * 8);
        gload16(cTh + (size_t)bh * 4096 + r * 64 + sc, chs + (j * 256 + (wv << 6)) * 8);
        gload16(cTl + (size_t)bh * 4096 + r * 64 + sc, cls + (j * 256 + (wv << 6)) * 8);
    }
    if (tid < 64) kcs[tid] = kcR[bh * 64 + tid];
    __syncthreads();                                      // drain gload16 + kcs
    {   // denom partials: 4 d-quarters x 64 rows in parallel
        int row = tid & 63, part = tid >> 6;
        float s = 0.f;
        #pragma unroll
        for (int i = 0; i < 16; ++i) {
            int d = part * 16 + i;
            unsigned short qv = *(const unsigned short*)((const char*)qs + row * 128 + ((d * 2) ^ ((row & 7) << 4)));
            s += b2f(qv) * kcs[d];
        }
        dpart[row][part] = s;
    }
    __syncthreads();
    if (tid < 64) dens[tid] = 1e-8f + dpart[tid][0] + dpart[tid][1] + dpart[tid][2] + dpart[tid][3];
    __syncthreads();

    f32x4 acc[4] = {};
    #pragma unroll
    for (int kk = 0; kk < 2; ++kk) {
        bf16x8 af = *(const bf16x8*)((const char*)qs + (wv * 16 + lr) * 128 + ((kk * 64 + lk * 16) ^ xorv));
        #pragma unroll
        for (int ni = 0; ni < 4; ++ni) {
            bf16x8 bh_ = *(const bf16x8*)((const char*)chs + (ni * 16 + lr) * 128 + ((kk * 64 + lk * 16) ^ xorv));
            bf16x8 bl_ = *(const bf16x8*)((const char*)cls + (ni * 16 + lr) * 128 + ((kk * 64 + lk * 16) ^ xorv));
            acc[ni] = __builtin_amdgcn_mfma_f32_16x16x32_bf16(af, bh_, acc[ni], 0, 0, 0);
            acc[ni] = __builtin_amdgcn_mfma_f32_16x16x32_bf16(af, bl_, acc[ni], 0, 0, 0);
        }
    }
    #pragma unroll
    for (int ni = 0; ni < 4; ++ni)
        #pragma unroll
        for (int r = 0; r < 4; ++r) {
            int n = wv * 16 + lk * 4 + r;
            float o = acc[ni][r] / dens[n];
            inner[(rowBase + n) * DMODEL + h * 64 + ni * 16 + lr] = f2b(o);
        }
}

extern "C" void kernel_launch(void* const* d_in, const int* in_sizes, int n_in,
                              void* d_out, int out_size, void* d_ws, size_t ws_size,
                              hipStream_t stream) {
    (void)in_sizes; (void)n_in; (void)out_size; (void)ws_size;
    const float* x    = (const float*)d_in[0];
    const float* wqkv = (const float*)d_in[1];
    const float* wout = (const float*)d_in[2];
    const float* bout = (const float*)d_in[3];

    char* w = (char*)d_ws;
    // Region [0, 32MB): xB (prep->gemm0), then ctxP+kcP (ctx->reduce), then inner (attn->gemm1)
    unsigned short* xB    = (unsigned short*)(w);                 // 32768*512*2  = 33554432
    float*          ctxP  = (float*)(w);                          // 8*64*4096*4  = 8388608
    float*          kcP   = (float*)(w + 8388608);                // 8*64*64*4    = 131072
    unsigned short* inner = (unsigned short*)(w);                 // 33554432
    unsigned short* qF    = (unsigned short*)(w + 33554432);      // 32768*512*2  = 33554432
    unsigned short* kT    = (unsigned short*)(w + 67108864);      // 64*64*4096*2 = 33554432
    unsigned short* vT    = (unsigned short*)(w + 100663296);     // 33554432
    unsigned short* wqkvB = (unsigned short*)(w + 134217728);     // 1572864
    unsigned short* woutB = (unsigned short*)(w + 135790592);     // 524288
    unsigned short* cTh   = (unsigned short*)(w + 136314880);     // 64*64*64*2   = 524288
    unsigned short* cTl   = (unsigned short*)(w + 136839168);     // 524288
    float*          kcR   = (float*)(w + 137363456);              // 64*64*4      = 16384
    // total ws usage: 137379840 bytes (< 144834560 proven available)

    hipLaunchKernelGGL(prep_kernel, dim3(2048), dim3(256), 0, stream,
                       x, wqkv, wout, xB, wqkvB, woutB);
    hipLaunchKernelGGL((gemm_kernel<0>), dim3(3072), dim3(256), 0, stream,
                       xB, wqkvB, (void*)qF, kT, vT, (const float*)nullptr,
                       NTOK, NQKV, DMODEL, 12);
    hipLaunchKernelGGL(ctx_kernel, dim3(NBH * NCHUNK), dim3(256), 0, stream, kT, vT, ctxP, kcP);
    hipLaunchKernelGGL(reduce_kernel, dim3(NBH), dim3(256), 0, stream, ctxP, kcP, cTh, cTl, kcR);
    hipLaunchKernelGGL(attn_kernel, dim3(NBH * 64), dim3(256), 0, stream, qF, cTh, cTl, kcR, inner);
    hipLaunchKernelGGL((gemm_kernel<1>), dim3(1024), dim3(256), 0, stream,
                       inner, woutB, (void*)d_out, (unsigned short*)nullptr, (unsigned short*)nullptr, bout,
                       NTOK, DMODEL, DMODEL, 4);
}